// Round 7
// baseline (628.968 us; speedup 1.0000x reference)
//
#include <hip/hip_runtime.h>
#include <math.h>

#define N_NODES 50000
#define N_EDGES 400000
#define LDH 136
#define WLDS (64 * LDH)   // f16 elems per wave-private act buffer (17408 B)

typedef _Float16 half8 __attribute__((ext_vector_type(8)));
typedef float f32x4 __attribute__((ext_vector_type(4)));

// workspace layout (bytes)
#define AGG_OFF 0           // 50000*64 f32
#define XH_OFF  12800000    // 50000*64 f16
#define UH_OFF  19200000    // 64*16 f16
#define WP_OFF  19202048    // packed weights, 200704 f16
// packed-weight offsets (f16 elements)
#define O_EW1 0
#define O_EH0 28672
#define O_EH1 45056
#define O_EWO 61440
#define O_AW1 69632
#define O_AH0 98304
#define O_AH1 114688
#define O_AWO 131072
#define O_NW1 139264
#define O_NH0 159744
#define O_NH1 176128
#define O_NWO 192512

__device__ __forceinline__ f32x4 mfma16(half8 a, half8 b, f32x4 c) {
  return __builtin_amdgcn_mfma_f32_16x16x32_f16(a, b, c, 0, 0, 0);
}

__device__ __forceinline__ half8 cvt8(float4 a, float4 b) {
  half8 v;
  v[0] = (_Float16)a.x; v[1] = (_Float16)a.y; v[2] = (_Float16)a.z; v[3] = (_Float16)a.w;
  v[4] = (_Float16)b.x; v[5] = (_Float16)b.y; v[6] = (_Float16)b.z; v[7] = (_Float16)b.w;
  return v;
}

__device__ __forceinline__ half8 zero8() {
  half8 v;
#pragma unroll
  for (int j = 0; j < 8; ++j) v[j] = (_Float16)0.f;
  return v;
}

// ---------------------------------------------------------------------------
// Hidden layer, wave-private, IN-PLACE: act[64][LDH], K=128 -> N=128, relu.
// All LDS reads complete (data-dep into acc) before any epilogue write issues,
// so in-place update is safe. No cross-wave sharing -> no barriers.
// ---------------------------------------------------------------------------
__device__ __forceinline__ void h_layer(_Float16* act, const half8* wp,
                                        const float* bias, int r, int ch) {
  f32x4 acc[4][8];
#pragma unroll
  for (int m = 0; m < 4; ++m)
#pragma unroll
    for (int n = 0; n < 8; ++n) acc[m][n] = (f32x4){0.f, 0.f, 0.f, 0.f};
#pragma unroll
  for (int s = 0; s < 4; ++s) {
    half8 B[8], A[4];
#pragma unroll
    for (int n = 0; n < 8; ++n) B[n] = wp[(s * 4 + ch) * 128 + n * 16 + r];
#pragma unroll
    for (int m = 0; m < 4; ++m)
      A[m] = *(const half8*)(act + (m * 16 + r) * LDH + s * 32 + ch * 8);
#pragma unroll
    for (int m = 0; m < 4; ++m)
#pragma unroll
      for (int n = 0; n < 8; ++n) acc[m][n] = mfma16(A[m], B[n], acc[m][n]);
  }
#pragma unroll
  for (int n = 0; n < 8; ++n) {
    float bb = bias[n * 16 + r];
#pragma unroll
    for (int m = 0; m < 4; ++m)
#pragma unroll
      for (int q = 0; q < 4; ++q)
        act[(m * 16 + ch * 4 + q) * LDH + n * 16 + r] =
            (_Float16)fmaxf(acc[m][n][q] + bb, 0.f);
  }
}

// ---------------------------------------------------------------------------
// Edge layer-1: per-lane global gather IS the A-fragment (K=224 padded).
// ---------------------------------------------------------------------------
__device__ __forceinline__ void l1_edge(const _Float16* __restrict__ x_h,
                                        const float* __restrict__ ea,
                                        const _Float16* __restrict__ u_h,
                                        _Float16* act, const half8* wp,
                                        const float* bias,
                                        const int* srcm, const int* tgtm, const int* ebm,
                                        int e0, int r, int ch) {
  f32x4 acc[4][8];
#pragma unroll
  for (int m = 0; m < 4; ++m)
#pragma unroll
    for (int n = 0; n < 8; ++n) acc[m][n] = (f32x4){0.f, 0.f, 0.f, 0.f};
#pragma unroll
  for (int s = 0; s < 7; ++s) {
    half8 B[8], A[4];
#pragma unroll
    for (int n = 0; n < 8; ++n) B[n] = wp[(s * 4 + ch) * 128 + n * 16 + r];
#pragma unroll
    for (int m = 0; m < 4; ++m) {
      if (s < 2) {
        A[m] = *(const half8*)(x_h + (size_t)srcm[m] * 64 + s * 32 + ch * 8);
      } else if (s < 4) {
        A[m] = *(const half8*)(x_h + (size_t)tgtm[m] * 64 + (s - 2) * 32 + ch * 8);
      } else if (s < 6) {
        const float* pe = ea + (size_t)(e0 + m * 16 + r) * 64 + (s - 4) * 32 + ch * 8;
        A[m] = cvt8(*(const float4*)pe, *(const float4*)(pe + 4));
      } else {
        A[m] = (ch < 2) ? *(const half8*)(u_h + ebm[m] * 16 + ch * 8) : zero8();
      }
    }
#pragma unroll
    for (int m = 0; m < 4; ++m)
#pragma unroll
      for (int n = 0; n < 8; ++n) acc[m][n] = mfma16(A[m], B[n], acc[m][n]);
  }
#pragma unroll
  for (int n = 0; n < 8; ++n) {
    float bb = bias[n * 16 + r];
#pragma unroll
    for (int m = 0; m < 4; ++m)
#pragma unroll
      for (int q = 0; q < 4; ++q)
        act[(m * 16 + ch * 4 + q) * LDH + n * 16 + r] =
            (_Float16)fmaxf(acc[m][n][q] + bb, 0.f);
  }
}

// ---------------------------------------------------------------------------
// Output layer (N=64) + bias + LayerNorm (normalized values left in acc).
// ---------------------------------------------------------------------------
__device__ __forceinline__ void out_layer(const _Float16* act, const half8* wpo,
                                          const float* bo, const float* g,
                                          const float* bt, f32x4 acc[4][4],
                                          int r, int ch) {
#pragma unroll
  for (int m = 0; m < 4; ++m)
#pragma unroll
    for (int t = 0; t < 4; ++t) acc[m][t] = (f32x4){0.f, 0.f, 0.f, 0.f};
#pragma unroll
  for (int s = 0; s < 4; ++s) {
    half8 B[4], A[4];
#pragma unroll
    for (int t = 0; t < 4; ++t) B[t] = wpo[(s * 4 + ch) * 64 + t * 16 + r];
#pragma unroll
    for (int m = 0; m < 4; ++m)
      A[m] = *(const half8*)(act + (m * 16 + r) * LDH + s * 32 + ch * 8);
#pragma unroll
    for (int m = 0; m < 4; ++m)
#pragma unroll
      for (int t = 0; t < 4; ++t) acc[m][t] = mfma16(A[m], B[t], acc[m][t]);
  }
  float bo4[4], g4[4], b4[4];
#pragma unroll
  for (int t = 0; t < 4; ++t) {
    bo4[t] = bo[t * 16 + r]; g4[t] = g[t * 16 + r]; b4[t] = bt[t * 16 + r];
  }
#pragma unroll
  for (int m = 0; m < 4; ++m)
#pragma unroll
    for (int t = 0; t < 4; ++t)
#pragma unroll
      for (int q = 0; q < 4; ++q) acc[m][t][q] += bo4[t];
#pragma unroll
  for (int m = 0; m < 4; ++m)
#pragma unroll
    for (int q = 0; q < 4; ++q) {
      float s1 = 0.f, s2 = 0.f;
#pragma unroll
      for (int t = 0; t < 4; ++t) { float v = acc[m][t][q]; s1 += v; s2 += v * v; }
#pragma unroll
      for (int mk = 1; mk < 16; mk <<= 1) {
        s1 += __shfl_xor(s1, mk); s2 += __shfl_xor(s2, mk);
      }
      float mu = s1 * (1.f / 64);
      float rs = rsqrtf(s2 * (1.f / 64) - mu * mu + 1e-5f);
#pragma unroll
      for (int t = 0; t < 4; ++t)
        acc[m][t][q] = (acc[m][t][q] - mu) * rs * g4[t] + b4[t];
    }
}

// ---------------------------------------------------------------------------
struct EdgeP {
  const float* edge_attr; const int* edge_index; const int* batch;
  const _Float16* x_h; const _Float16* u_h; const _Float16* wp;
  const float *eBin, *eBh, *eBout, *eG, *eBt;
  const float *aBin, *aBh, *aBout, *aG, *aBt;
  float* agg;
};

// Each WAVE owns 64 edges end-to-end. Wave-private LDS act buffer; ZERO
// __syncthreads. 4 waves/block, LDS 69632 B -> 2 blocks/CU (8 indep waves).
__global__ __launch_bounds__(256, 2) void edge_kernel(EdgeP p) {
  __shared__ __align__(16) _Float16 sAct[4 * WLDS];
  const int tid = threadIdx.x, lane = tid & 63, w = tid >> 6;
  const int r = lane & 15, ch = lane >> 4;
  const int wgid = blockIdx.x * 4 + w;
  const int e0 = wgid * 64;
  if (e0 >= N_EDGES) return;
  _Float16* act = sAct + w * WLDS;

  int srcm[4], tgtm[4], ebm[4];
#pragma unroll
  for (int m = 0; m < 4; ++m) srcm[m] = p.edge_index[e0 + m * 16 + r];
#pragma unroll
  for (int m = 0; m < 4; ++m) tgtm[m] = p.edge_index[N_EDGES + e0 + m * 16 + r];
#pragma unroll
  for (int m = 0; m < 4; ++m) ebm[m] = p.batch[srcm[m]];

  // ---- e-path ----
  l1_edge(p.x_h, p.edge_attr, p.u_h, act, (const half8*)(p.wp + O_EW1), p.eBin,
          srcm, tgtm, ebm, e0, r, ch);
  h_layer(act, (const half8*)(p.wp + O_EH0), p.eBh, r, ch);
  h_layer(act, (const half8*)(p.wp + O_EH1), p.eBh + 128, r, ch);
  f32x4 accE[4][4];
  out_layer(act, (const half8*)(p.wp + O_EWO), p.eBout, p.eG, p.eBt, accE, r, ch);
  // pack normalized e-out into 8 half8 (32 VGPR), freeing accE
  half8 eP[8];
#pragma unroll
  for (int m = 0; m < 4; ++m)
#pragma unroll
    for (int h = 0; h < 2; ++h) {
      half8 v;
#pragma unroll
      for (int tt = 0; tt < 2; ++tt)
#pragma unroll
        for (int q = 0; q < 4; ++q)
          v[tt * 4 + q] = (_Float16)accE[m][h * 2 + tt][q];
      eP[m * 2 + h] = v;
    }

  // ---- a-path ----
  l1_edge(p.x_h, p.edge_attr, p.u_h, act, (const half8*)(p.wp + O_AW1), p.aBin,
          srcm, tgtm, ebm, e0, r, ch);
  h_layer(act, (const half8*)(p.wp + O_AH0), p.aBh, r, ch);
  h_layer(act, (const half8*)(p.wp + O_AH1), p.aBh + 128, r, ch);
  f32x4 accA[4][4];
  out_layer(act, (const half8*)(p.wp + O_AWO), p.aBout, p.aG, p.aBt, accA, r, ch);

  // ---- combine: sigmoid(a) * e -> atomic scatter ----
#pragma unroll
  for (int m = 0; m < 4; ++m)
#pragma unroll
    for (int q = 0; q < 4; ++q) {
      int tq = p.edge_index[N_EDGES + e0 + m * 16 + ch * 4 + q];
      float* ap = p.agg + (size_t)tq * 64 + r;
#pragma unroll
      for (int t = 0; t < 4; ++t) {
        float sg = 1.f / (1.f + __expf(-accA[m][t][q]));
        float oe = (float)eP[m * 2 + (t >> 1)][(t & 1) * 4 + q];
        atomicAdd(ap + t * 16, oe * sg);
      }
    }
}

// ---------------------------------------------------------------------------
struct NodeP {
  const float* agg; const _Float16* x_h; const _Float16* u_h;
  const _Float16* wp; const int* batch;
  const float *Bin, *Bh, *Bout, *G, *Bt;
  float* out;
};

__global__ __launch_bounds__(256, 2) void node_kernel(NodeP p) {
  __shared__ __align__(16) _Float16 sAct[4 * WLDS];
  const int tid = threadIdx.x, lane = tid & 63, w = tid >> 6;
  const int r = lane & 15, ch = lane >> 4;
  const int wgid = blockIdx.x * 4 + w;
  const int n0 = wgid * 64;
  if (n0 >= N_NODES) return;
  _Float16* act = sAct + w * WLDS;

  int nm[4], bm[4];
#pragma unroll
  for (int m = 0; m < 4; ++m) {
    int n = n0 + m * 16 + r;
    nm[m] = (n < N_NODES) ? n : 0;
  }
#pragma unroll
  for (int m = 0; m < 4; ++m) bm[m] = p.batch[nm[m]];

  // L1: K = 160 padded (x 64 | agg 64 | u 16 | pad)
  {
    f32x4 acc[4][8];
#pragma unroll
    for (int m = 0; m < 4; ++m)
#pragma unroll
      for (int n = 0; n < 8; ++n) acc[m][n] = (f32x4){0.f, 0.f, 0.f, 0.f};
    const half8* wp = (const half8*)(p.wp + O_NW1);
#pragma unroll
    for (int s = 0; s < 5; ++s) {
      half8 B[8], A[4];
#pragma unroll
      for (int n = 0; n < 8; ++n) B[n] = wp[(s * 4 + ch) * 128 + n * 16 + r];
#pragma unroll
      for (int m = 0; m < 4; ++m) {
        if (s < 2) {
          A[m] = *(const half8*)(p.x_h + (size_t)nm[m] * 64 + s * 32 + ch * 8);
        } else if (s < 4) {
          const float* ag = p.agg + (size_t)nm[m] * 64 + (s - 2) * 32 + ch * 8;
          A[m] = cvt8(*(const float4*)ag, *(const float4*)(ag + 4));
        } else {
          A[m] = (ch < 2) ? *(const half8*)(p.u_h + bm[m] * 16 + ch * 8) : zero8();
        }
      }
#pragma unroll
      for (int m = 0; m < 4; ++m)
#pragma unroll
        for (int n = 0; n < 8; ++n) acc[m][n] = mfma16(A[m], B[n], acc[m][n]);
    }
#pragma unroll
    for (int n = 0; n < 8; ++n) {
      float bb = p.Bin[n * 16 + r];
#pragma unroll
      for (int m = 0; m < 4; ++m)
#pragma unroll
        for (int q = 0; q < 4; ++q)
          act[(m * 16 + ch * 4 + q) * LDH + n * 16 + r] =
              (_Float16)fmaxf(acc[m][n][q] + bb, 0.f);
    }
  }

  h_layer(act, (const half8*)(p.wp + O_NH0), p.Bh, r, ch);
  h_layer(act, (const half8*)(p.wp + O_NH1), p.Bh + 128, r, ch);
  f32x4 acc[4][4];
  out_layer(act, (const half8*)(p.wp + O_NWO), p.Bout, p.G, p.Bt, acc, r, ch);

#pragma unroll
  for (int m = 0; m < 4; ++m)
#pragma unroll
    for (int q = 0; q < 4; ++q) {
      int n = n0 + m * 16 + ch * 4 + q;
      if (n < N_NODES) {
#pragma unroll
        for (int t = 0; t < 4; ++t)
          p.out[(size_t)n * 64 + t * 16 + r] = acc[m][t][q];
      }
    }
}

// ---------------------------------------------------------------------------
// Per-call pack: fp32 weights -> MFMA-B-fragment-packed fp16; x,u -> fp16.
// wdst[((s*4+c)*N + n)*8 + j] = W[s*32+c*8+j][n]  (0 if k >= Kreal)
// ---------------------------------------------------------------------------
#define GX 112
struct PackP {
  const float* src[12];
  int Kreal[12], Nlog[12], size[12], dstoff[12];
  const float* x; const float* u;
  _Float16* x_h; _Float16* u_h; _Float16* wdst;
};

__global__ void pack_kernel(PackP p) {
  int y = blockIdx.y;
  int idx = blockIdx.x * 256 + threadIdx.x;
  if (y < 12) {
    int sz = p.size[y];
    if (idx >= sz) return;
    int N = 1 << p.Nlog[y];
    int j = idx & 7, t = idx >> 3;
    int n = t & (N - 1);
    int sc = t >> p.Nlog[y];
    int c = sc & 3, s = sc >> 2;
    int k = s * 32 + c * 8 + j;
    p.wdst[p.dstoff[y] + idx] =
        (k < p.Kreal[y]) ? (_Float16)p.src[y][k * N + n] : (_Float16)0.f;
  } else {
    for (int i = idx; i < N_NODES * 64; i += GX * 256) p.x_h[i] = (_Float16)p.x[i];
    for (int i = idx; i < 64 * 16; i += GX * 256) p.u_h[i] = (_Float16)p.u[i];
  }
}

// ---------------------------------------------------------------------------
extern "C" void kernel_launch(void* const* d_in, const int* in_sizes, int n_in,
                              void* d_out, int out_size, void* d_ws, size_t ws_size,
                              hipStream_t stream) {
  const float* x = (const float*)d_in[0];
  const float* edge_attr = (const float*)d_in[1];
  const float* u = (const float*)d_in[2];
  const int* edge_index = (const int*)d_in[3];
  const int* batch = (const int*)d_in[4];

  char* ws = (char*)d_ws;
  float* agg = (float*)(ws + AGG_OFF);
  _Float16* x_h = (_Float16*)(ws + XH_OFF);
  _Float16* u_h = (_Float16*)(ws + UH_OFF);
  _Float16* wp = (_Float16*)(ws + WP_OFF);

  hipMemsetAsync(agg, 0, (size_t)N_NODES * 64 * sizeof(float), stream);

  PackP pk;
  const float* eWh = (const float*)d_in[7];
  const float* aWh = (const float*)d_in[15];
  const float* nWh = (const float*)d_in[23];
  const float* srcs[12] = {
      (const float*)d_in[5], eWh, eWh + 16384, (const float*)d_in[9],
      (const float*)d_in[13], aWh, aWh + 16384, (const float*)d_in[17],
      (const float*)d_in[21], nWh, nWh + 16384, (const float*)d_in[25]};
  const int kr[12] = {208, 128, 128, 128, 208, 128, 128, 128, 144, 128, 128, 128};
  const int nl[12] = {7, 7, 7, 6, 7, 7, 7, 6, 7, 7, 7, 6};
  const int sz[12] = {28672, 16384, 16384, 8192, 28672, 16384, 16384, 8192,
                      20480, 16384, 16384, 8192};
  const int off[12] = {O_EW1, O_EH0, O_EH1, O_EWO, O_AW1, O_AH0, O_AH1, O_AWO,
                       O_NW1, O_NH0, O_NH1, O_NWO};
  for (int i = 0; i < 12; ++i) {
    pk.src[i] = srcs[i]; pk.Kreal[i] = kr[i]; pk.Nlog[i] = nl[i];
    pk.size[i] = sz[i]; pk.dstoff[i] = off[i];
  }
  pk.x = x; pk.u = u; pk.x_h = x_h; pk.u_h = u_h; pk.wdst = wp;
  pack_kernel<<<dim3(GX, 13), 256, 0, stream>>>(pk);

  EdgeP ep;
  ep.edge_attr = edge_attr; ep.edge_index = edge_index; ep.batch = batch;
  ep.x_h = x_h; ep.u_h = u_h; ep.wp = wp;
  ep.eBin = (const float*)d_in[6];  ep.eBh = (const float*)d_in[8];
  ep.eBout = (const float*)d_in[10]; ep.eG = (const float*)d_in[11];
  ep.eBt = (const float*)d_in[12];
  ep.aBin = (const float*)d_in[14]; ep.aBh = (const float*)d_in[16];
  ep.aBout = (const float*)d_in[18]; ep.aG = (const float*)d_in[19];
  ep.aBt = (const float*)d_in[20];
  ep.agg = agg;
  // 6250 waves of 64 edges, 4 waves/block
  edge_kernel<<<(6250 + 3) / 4, 256, 0, stream>>>(ep);

  NodeP np;
  np.agg = agg; np.x_h = x_h; np.u_h = u_h; np.wp = wp; np.batch = batch;
  np.Bin = (const float*)d_in[22]; np.Bh = (const float*)d_in[24];
  np.Bout = (const float*)d_in[26]; np.G = (const float*)d_in[27];
  np.Bt = (const float*)d_in[28];
  np.out = (float*)d_out;
  // 782 waves of 64 nodes, 4 waves/block
  node_kernel<<<(784 + 3) / 4, 256, 0, stream>>>(np);
}

// Round 9
// 564.610 us; speedup vs baseline: 1.1140x; 1.1140x over previous
//
#include <hip/hip_runtime.h>
#include <math.h>

#define N_NODES 50000
#define N_EDGES 400000
#define LD1 232   // edge L1 input ld (208 -> 224 + 8 pad)
#define LDH 136   // hidden ld (128 + 8)
#define LDN 168   // node L1 input ld (144 -> 160 + 8)

typedef _Float16 half8 __attribute__((ext_vector_type(8)));
typedef float f32x4 __attribute__((ext_vector_type(4)));

// workspace layout (bytes)
#define AGG_OFF 0           // 50000*64 f32
#define XH_OFF  12800000    // 50000*64 f16
#define UH_OFF  19200000    // 64*16 f16
#define WP_OFF  19202048    // packed weights, 200704 f16
// packed-weight offsets (f16 elements)
#define O_EW1 0
#define O_EH0 28672
#define O_EH1 45056
#define O_EWO 61440
#define O_AW1 69632
#define O_AH0 98304
#define O_AH1 114688
#define O_AWO 131072
#define O_NW1 139264
#define O_NH0 159744
#define O_NH1 176128
#define O_NWO 192512

__device__ __forceinline__ f32x4 mfma16(half8 a, half8 b, f32x4 c) {
  return __builtin_amdgcn_mfma_f32_16x16x32_f16(a, b, c, 0, 0, 0);
}

__device__ __forceinline__ half8 cvt8(float4 a, float4 b) {
  half8 v;
  v[0] = (_Float16)a.x; v[1] = (_Float16)a.y; v[2] = (_Float16)a.z; v[3] = (_Float16)a.w;
  v[4] = (_Float16)b.x; v[5] = (_Float16)b.y; v[6] = (_Float16)b.z; v[7] = (_Float16)b.w;
  return v;
}

__device__ __forceinline__ half8 zero8() {
  half8 v;
#pragma unroll
  for (int j = 0; j < 8; ++j) v[j] = (_Float16)0.f;
  return v;
}

// ---------------------------------------------------------------------------
// GEMM stage, M=32 rows: dst[0:32][w*32..+32) = relu(src[0:32][0:NS*32] @ W+b)
// All 4 waves active (wave w owns a 32-col slice). B preloaded to registers.
// ---------------------------------------------------------------------------
template<int NS, int LDSRC>
__device__ __forceinline__ void gemm_m2(const _Float16* __restrict__ src,
                                        _Float16* __restrict__ dst,
                                        const half8* __restrict__ wp,
                                        const float* __restrict__ bias,
                                        int w, int lane) {
  const int r = lane & 15, ch = lane >> 4;
  half8 B0[NS], B1[NS];
#pragma unroll
  for (int s = 0; s < NS; ++s) {
    B0[s] = wp[(s * 4 + ch) * 128 + w * 32 + r];
    B1[s] = wp[(s * 4 + ch) * 128 + w * 32 + 16 + r];
  }
  f32x4 a0[2], a1[2];
#pragma unroll
  for (int m = 0; m < 2; ++m) {
    a0[m] = (f32x4){0.f, 0.f, 0.f, 0.f};
    a1[m] = (f32x4){0.f, 0.f, 0.f, 0.f};
  }
#pragma unroll
  for (int s = 0; s < NS; ++s) {
#pragma unroll
    for (int m = 0; m < 2; ++m) {
      half8 a = *(const half8*)(src + (m * 16 + r) * LDSRC + s * 32 + ch * 8);
      a0[m] = mfma16(a, B0[s], a0[m]);
      a1[m] = mfma16(a, B1[s], a1[m]);
    }
  }
  float bb0 = bias[w * 32 + r], bb1 = bias[w * 32 + 16 + r];
#pragma unroll
  for (int m = 0; m < 2; ++m)
#pragma unroll
    for (int q = 0; q < 4; ++q) {
      int row = m * 16 + ch * 4 + q;
      dst[row * LDH + w * 32 + r]      = (_Float16)fmaxf(a0[m][q] + bb0, 0.f);
      dst[row * LDH + w * 32 + 16 + r] = (_Float16)fmaxf(a1[m][q] + bb1, 0.f);
    }
}

// ---------------------------------------------------------------------------
// Output layer for ONE 16-row slab (wave w in {0,1} owns rows w*16..+16),
// all 64 cols. Result: normalized (LayerNorm'd) values left in acc[t][q],
// layout C[row = w*16 + ch*4 + q][col = t*16 + r].
// ---------------------------------------------------------------------------
__device__ __forceinline__ void out16(const _Float16* __restrict__ src,
                                      const half8* __restrict__ wpo,
                                      const float* __restrict__ bo,
                                      const float* __restrict__ g,
                                      const float* __restrict__ bt,
                                      f32x4 acc[4], int w, int lane) {
  const int r = lane & 15, ch = lane >> 4;
  half8 BO[4][4];
#pragma unroll
  for (int s = 0; s < 4; ++s)
#pragma unroll
    for (int t = 0; t < 4; ++t) BO[s][t] = wpo[(s * 4 + ch) * 64 + t * 16 + r];
#pragma unroll
  for (int t = 0; t < 4; ++t) acc[t] = (f32x4){0.f, 0.f, 0.f, 0.f};
#pragma unroll
  for (int s = 0; s < 4; ++s) {
    half8 a = *(const half8*)(src + (w * 16 + r) * LDH + s * 32 + ch * 8);
#pragma unroll
    for (int t = 0; t < 4; ++t) acc[t] = mfma16(a, BO[s][t], acc[t]);
  }
  float g4[4], b4[4];
#pragma unroll
  for (int t = 0; t < 4; ++t) {
    float bv = bo[t * 16 + r];
#pragma unroll
    for (int q = 0; q < 4; ++q) acc[t][q] += bv;
    g4[t] = g[t * 16 + r]; b4[t] = bt[t * 16 + r];
  }
#pragma unroll
  for (int q = 0; q < 4; ++q) {
    float s1 = 0.f, s2 = 0.f;
#pragma unroll
    for (int t = 0; t < 4; ++t) { float v = acc[t][q]; s1 += v; s2 += v * v; }
#pragma unroll
    for (int mk = 1; mk < 16; mk <<= 1) {
      s1 += __shfl_xor(s1, mk); s2 += __shfl_xor(s2, mk);
    }
    float mu = s1 * (1.f / 64);
    float rs = rsqrtf(s2 * (1.f / 64) - mu * mu + 1e-5f);
#pragma unroll
    for (int t = 0; t < 4; ++t)
      acc[t][q] = (acc[t][q] - mu) * rs * g4[t] + b4[t];
  }
}

// ---------------------------------------------------------------------------
struct EdgeP {
  const float* edge_attr; const int* edge_index; const int* batch;
  const _Float16* x_h; const _Float16* u_h; const _Float16* wp;
  const float *eBin, *eBh, *eBout, *eG, *eBt;
  const float *aBin, *aBh, *aBout, *aG, *aBt;
  float* agg;
};

// 32 edges/block, 256 threads (4 waves). sIn staged ONCE, read by BOTH L1s.
// LDS = 14848 + 2*8704 = 32256 B -> 4+ blocks/CU (VGPR-capped at 4):
// 4 independent barrier groups per CU.
__global__ __launch_bounds__(256, 4) void edge_kernel(EdgeP p) {
  __shared__ __align__(16) _Float16 sIn[32 * LD1];
  __shared__ __align__(16) _Float16 sA[32 * LDH];
  __shared__ __align__(16) _Float16 sB[32 * LDH];
  const int tid = threadIdx.x, lane = tid & 63, w = tid >> 6;
  const int r = lane & 15, ch = lane >> 4;
  const int e0 = blockIdx.x * 32;

  // stage neigh = [x[src] | x[tgt] | edge_attr | u[batch[src]] | 0-pad] f16
  for (int idx = tid; idx < 32 * 32; idx += 256) {
    int c = idx & 31, e = idx >> 5;
    if (c >= 28) continue;
    int col = c * 8;
    half8 v;
    if (col < 64) {
      int s = p.edge_index[e0 + e];
      v = *(const half8*)(p.x_h + (size_t)s * 64 + col);
    } else if (col < 128) {
      int t = p.edge_index[N_EDGES + e0 + e];
      v = *(const half8*)(p.x_h + (size_t)t * 64 + col - 64);
    } else if (col < 192) {
      const float* ea = p.edge_attr + (size_t)(e0 + e) * 64 + (col - 128);
      v = cvt8(*(const float4*)ea, *(const float4*)(ea + 4));
    } else if (col < 208) {
      int s = p.edge_index[e0 + e];
      int eb = p.batch[s];
      v = *(const half8*)(p.u_h + eb * 16 + col - 192);
    } else {
      v = zero8();
    }
    *(half8*)(sIn + e * LD1 + col) = v;
  }
  __syncthreads();

  // ---- e-path ----
  gemm_m2<7, LD1>(sIn, sA, (const half8*)(p.wp + O_EW1), p.eBin, w, lane);
  __syncthreads();
  gemm_m2<4, LDH>(sA, sB, (const half8*)(p.wp + O_EH0), p.eBh, w, lane);
  __syncthreads();
  gemm_m2<4, LDH>(sB, sA, (const half8*)(p.wp + O_EH1), p.eBh + 128, w, lane);
  __syncthreads();
  half8 eP0 = zero8(), eP1 = zero8();
  if (w < 2) {
    f32x4 aE[4];
    out16(sA, (const half8*)(p.wp + O_EWO), p.eBout, p.eG, p.eBt, aE, w, lane);
#pragma unroll
    for (int q = 0; q < 4; ++q) {
      eP0[q] = (_Float16)aE[0][q]; eP0[4 + q] = (_Float16)aE[1][q];
      eP1[q] = (_Float16)aE[2][q]; eP1[4 + q] = (_Float16)aE[3][q];
    }
  }
  __syncthreads();  // sA free for a-path

  // ---- a-path (reads the same sIn) ----
  gemm_m2<7, LD1>(sIn, sA, (const half8*)(p.wp + O_AW1), p.aBin, w, lane);
  __syncthreads();
  gemm_m2<4, LDH>(sA, sB, (const half8*)(p.wp + O_AH0), p.aBh, w, lane);
  __syncthreads();
  gemm_m2<4, LDH>(sB, sA, (const half8*)(p.wp + O_AH1), p.aBh + 128, w, lane);
  __syncthreads();
  if (w < 2) {
    f32x4 aA[4];
    out16(sA, (const half8*)(p.wp + O_AWO), p.aBout, p.aG, p.aBt, aA, w, lane);
    int tq[4];
#pragma unroll
    for (int q = 0; q < 4; ++q)
      tq[q] = p.edge_index[N_EDGES + e0 + w * 16 + ch * 4 + q];
#pragma unroll
    for (int q = 0; q < 4; ++q) {
      float* ap = p.agg + (size_t)tq[q] * 64 + r;
#pragma unroll
      for (int t = 0; t < 4; ++t) {
        float sg = 1.f / (1.f + __expf(-aA[t][q]));
        float oe = (t < 2) ? (float)eP0[t * 4 + q] : (float)eP1[(t - 2) * 4 + q];
        atomicAdd(ap + t * 16, oe * sg);
      }
    }
  }
}

// ---------------------------------------------------------------------------
struct NodeP {
  const float* agg; const _Float16* x_h; const _Float16* u_h;
  const _Float16* wp; const int* batch;
  const float *Bin, *Bh, *Bout, *G, *Bt;
  float* out;
};

// 32 nodes/block, 256 threads. LDS = 10752 + 2*8704 = 28160 B.
__global__ __launch_bounds__(256, 4) void node_kernel(NodeP p) {
  __shared__ __align__(16) _Float16 sIn[32 * LDN];
  __shared__ __align__(16) _Float16 sA[32 * LDH];
  __shared__ __align__(16) _Float16 sB[32 * LDH];
  const int tid = threadIdx.x, lane = tid & 63, w = tid >> 6;
  const int r = lane & 15, ch = lane >> 4;
  const int n0 = blockIdx.x * 32;

  // stage [x | agg | u | 0-pad] as f16
  for (int idx = tid; idx < 32 * 32; idx += 256) {
    int c = idx & 31, e = idx >> 5;
    if (c >= 20) continue;
    int n = n0 + e, col = c * 8;
    half8 v;
    if (n >= N_NODES || col >= 144) {
      v = zero8();
    } else if (col < 64) {
      v = *(const half8*)(p.x_h + (size_t)n * 64 + col);
    } else if (col < 128) {
      const float* ag = p.agg + (size_t)n * 64 + (col - 64);
      v = cvt8(*(const float4*)ag, *(const float4*)(ag + 4));
    } else {
      v = *(const half8*)(p.u_h + p.batch[n] * 16 + col - 128);
    }
    *(half8*)(sIn + e * LDN + col) = v;
  }
  __syncthreads();

  gemm_m2<5, LDN>(sIn, sA, (const half8*)(p.wp + O_NW1), p.Bin, w, lane);
  __syncthreads();
  gemm_m2<4, LDH>(sA, sB, (const half8*)(p.wp + O_NH0), p.Bh, w, lane);
  __syncthreads();
  gemm_m2<4, LDH>(sB, sA, (const half8*)(p.wp + O_NH1), p.Bh + 128, w, lane);
  __syncthreads();
  if (w < 2) {
    f32x4 acc[4];
    out16(sA, (const half8*)(p.wp + O_NWO), p.Bout, p.G, p.Bt, acc, w, lane);
#pragma unroll
    for (int q = 0; q < 4; ++q) {
      int n = n0 + w * 16 + ch * 4 + q;
      if (n < N_NODES) {
#pragma unroll
        for (int t = 0; t < 4; ++t)
          p.out[(size_t)n * 64 + t * 16 + r] = acc[t][q];
      }
    }
  }
}

// ---------------------------------------------------------------------------
// Per-call pack: fp32 weights -> MFMA-B-fragment-packed fp16; x,u -> fp16.
// wdst[((s*4+c)*N + n)*8 + j] = W[s*32+c*8+j][n]  (0 if k >= Kreal)
// ---------------------------------------------------------------------------
#define GX 112
struct PackP {
  const float* src[12];
  int Kreal[12], Nlog[12], size[12], dstoff[12];
  const float* x; const float* u;
  _Float16* x_h; _Float16* u_h; _Float16* wdst;
};

__global__ void pack_kernel(PackP p) {
  int y = blockIdx.y;
  int idx = blockIdx.x * 256 + threadIdx.x;
  if (y < 12) {
    int sz = p.size[y];
    if (idx >= sz) return;
    int N = 1 << p.Nlog[y];
    int j = idx & 7, t = idx >> 3;
    int n = t & (N - 1);
    int sc = t >> p.Nlog[y];
    int c = sc & 3, s = sc >> 2;
    int k = s * 32 + c * 8 + j;
    p.wdst[p.dstoff[y] + idx] =
        (k < p.Kreal[y]) ? (_Float16)p.src[y][k * N + n] : (_Float16)0.f;
  } else {
    for (int i = idx; i < N_NODES * 64; i += GX * 256) p.x_h[i] = (_Float16)p.x[i];
    for (int i = idx; i < 64 * 16; i += GX * 256) p.u_h[i] = (_Float16)p.u[i];
  }
}

// ---------------------------------------------------------------------------
extern "C" void kernel_launch(void* const* d_in, const int* in_sizes, int n_in,
                              void* d_out, int out_size, void* d_ws, size_t ws_size,
                              hipStream_t stream) {
  const float* x = (const float*)d_in[0];
  const float* edge_attr = (const float*)d_in[1];
  const float* u = (const float*)d_in[2];
  const int* edge_index = (const int*)d_in[3];
  const int* batch = (const int*)d_in[4];

  char* ws = (char*)d_ws;
  float* agg = (float*)(ws + AGG_OFF);
  _Float16* x_h = (_Float16*)(ws + XH_OFF);
  _Float16* u_h = (_Float16*)(ws + UH_OFF);
  _Float16* wp = (_Float16*)(ws + WP_OFF);

  hipMemsetAsync(agg, 0, (size_t)N_NODES * 64 * sizeof(float), stream);

  PackP pk;
  const float* eWh = (const float*)d_in[7];
  const float* aWh = (const float*)d_in[15];
  const float* nWh = (const float*)d_in[23];
  const float* srcs[12] = {
      (const float*)d_in[5], eWh, eWh + 16384, (const float*)d_in[9],
      (const float*)d_in[13], aWh, aWh + 16384, (const float*)d_in[17],
      (const float*)d_in[21], nWh, nWh + 16384, (const float*)d_in[25]};
  const int kr[12] = {208, 128, 128, 128, 208, 128, 128, 128, 144, 128, 128, 128};
  const int nl[12] = {7, 7, 7, 6, 7, 7, 7, 6, 7, 7, 7, 6};
  const int sz[12] = {28672, 16384, 16384, 8192, 28672, 16384, 16384, 8192,
                      20480, 16384, 16384, 8192};
  const int off[12] = {O_EW1, O_EH0, O_EH1, O_EWO, O_AW1, O_AH0, O_AH1, O_AWO,
                       O_NW1, O_NH0, O_NH1, O_NWO};
  for (int i = 0; i < 12; ++i) {
    pk.src[i] = srcs[i]; pk.Kreal[i] = kr[i]; pk.Nlog[i] = nl[i];
    pk.size[i] = sz[i]; pk.dstoff[i] = off[i];
  }
  pk.x = x; pk.u = u; pk.x_h = x_h; pk.u_h = u_h; pk.wdst = wp;
  pack_kernel<<<dim3(GX, 13), 256, 0, stream>>>(pk);

  EdgeP ep;
  ep.edge_attr = edge_attr; ep.edge_index = edge_index; ep.batch = batch;
  ep.x_h = x_h; ep.u_h = u_h; ep.wp = wp;
  ep.eBin = (const float*)d_in[6];  ep.eBh = (const float*)d_in[8];
  ep.eBout = (const float*)d_in[10]; ep.eG = (const float*)d_in[11];
  ep.eBt = (const float*)d_in[12];
  ep.aBin = (const float*)d_in[14]; ep.aBh = (const float*)d_in[16];
  ep.aBout = (const float*)d_in[18]; ep.aG = (const float*)d_in[19];
  ep.aBt = (const float*)d_in[20];
  ep.agg = agg;
  edge_kernel<<<N_EDGES / 32, 256, 0, stream>>>(ep);

  NodeP np;
  np.agg = agg; np.x_h = x_h; np.u_h = u_h; np.wp = wp; np.batch = batch;
  np.Bin = (const float*)d_in[22]; np.Bh = (const float*)d_in[24];
  np.Bout = (const float*)d_in[26]; np.G = (const float*)d_in[27];
  np.Bt = (const float*)d_in[28];
  np.out = (float*)d_out;
  node_kernel<<<(N_NODES + 31) / 32, 256, 0, stream>>>(np);
}

// Round 10
// 535.229 us; speedup vs baseline: 1.1751x; 1.0549x over previous
//
#include <hip/hip_runtime.h>
#include <math.h>

#define N_NODES 50000
#define N_EDGES 400000
#define LD1 232   // edge L1 input ld (208 -> 224 + 8 pad)
#define LDH 136   // hidden ld (128 + 8)
#define LDN 168   // node L1 input ld (144 -> 160 + 8)

typedef _Float16 half8 __attribute__((ext_vector_type(8)));
typedef float f32x4 __attribute__((ext_vector_type(4)));

// workspace layout (bytes)
#define AGG_OFF 0           // 50000*64 f32
#define XH_OFF  12800000    // 50000*64 f16
#define UH_OFF  19200000    // 64*16 f16
#define WP_OFF  19202048    // packed weights, 200704 f16
// packed-weight offsets (f16 elements)
#define O_EW1 0
#define O_EH0 28672
#define O_EH1 45056
#define O_EWO 61440
#define O_AW1 69632
#define O_AH0 98304
#define O_AH1 114688
#define O_AWO 131072
#define O_NW1 139264
#define O_NH0 159744
#define O_NH1 176128
#define O_NWO 192512

__device__ __forceinline__ f32x4 mfma16(half8 a, half8 b, f32x4 c) {
  return __builtin_amdgcn_mfma_f32_16x16x32_f16(a, b, c, 0, 0, 0);
}

__device__ __forceinline__ half8 cvt8(float4 a, float4 b) {
  half8 v;
  v[0] = (_Float16)a.x; v[1] = (_Float16)a.y; v[2] = (_Float16)a.z; v[3] = (_Float16)a.w;
  v[4] = (_Float16)b.x; v[5] = (_Float16)b.y; v[6] = (_Float16)b.z; v[7] = (_Float16)b.w;
  return v;
}

__device__ __forceinline__ half8 zero8() {
  half8 v;
#pragma unroll
  for (int j = 0; j < 8; ++j) v[j] = (_Float16)0.f;
  return v;
}

// ---------------------------------------------------------------------------
// 64-col GEMM slice, M=32: dst[0:32][col0..col0+64) = relu(src @ W + b).
// One wave handles 4 col-tiles x 2 row-tiles -> NS*8 MFMAs per call (long
// burst amortizes per-stage latency).
// ---------------------------------------------------------------------------
template<int NS, int LDSRC>
__device__ __forceinline__ void gemm64(const _Float16* __restrict__ src,
                                       _Float16* __restrict__ dst,
                                       const half8* __restrict__ wp,
                                       const float* __restrict__ bias,
                                       int col0, int lane) {
  const int r = lane & 15, ch = lane >> 4;
  f32x4 acc[2][4];
#pragma unroll
  for (int m = 0; m < 2; ++m)
#pragma unroll
    for (int t = 0; t < 4; ++t) acc[m][t] = (f32x4){0.f, 0.f, 0.f, 0.f};
#pragma unroll
  for (int s = 0; s < NS; ++s) {
    half8 B[4];
#pragma unroll
    for (int t = 0; t < 4; ++t) B[t] = wp[(s * 4 + ch) * 128 + col0 + t * 16 + r];
    half8 A0 = *(const half8*)(src + r * LDSRC + s * 32 + ch * 8);
    half8 A1 = *(const half8*)(src + (16 + r) * LDSRC + s * 32 + ch * 8);
#pragma unroll
    for (int t = 0; t < 4; ++t) {
      acc[0][t] = mfma16(A0, B[t], acc[0][t]);
      acc[1][t] = mfma16(A1, B[t], acc[1][t]);
    }
  }
#pragma unroll
  for (int t = 0; t < 4; ++t) {
    float bb = bias[col0 + t * 16 + r];
#pragma unroll
    for (int m = 0; m < 2; ++m)
#pragma unroll
      for (int q = 0; q < 4; ++q)
        dst[(m * 16 + ch * 4 + q) * LDH + col0 + t * 16 + r] =
            (_Float16)fmaxf(acc[m][t][q] + bb, 0.f);
  }
}

// 32-col GEMM slice (node kernel): 4 waves cover 128 cols.
template<int NS, int LDSRC>
__device__ __forceinline__ void gemm_m2(const _Float16* __restrict__ src,
                                        _Float16* __restrict__ dst,
                                        const half8* __restrict__ wp,
                                        const float* __restrict__ bias,
                                        int w, int lane) {
  const int r = lane & 15, ch = lane >> 4;
  f32x4 a0[2], a1[2];
#pragma unroll
  for (int m = 0; m < 2; ++m) {
    a0[m] = (f32x4){0.f, 0.f, 0.f, 0.f};
    a1[m] = (f32x4){0.f, 0.f, 0.f, 0.f};
  }
#pragma unroll
  for (int s = 0; s < NS; ++s) {
    half8 B0 = wp[(s * 4 + ch) * 128 + w * 32 + r];
    half8 B1 = wp[(s * 4 + ch) * 128 + w * 32 + 16 + r];
#pragma unroll
    for (int m = 0; m < 2; ++m) {
      half8 a = *(const half8*)(src + (m * 16 + r) * LDSRC + s * 32 + ch * 8);
      a0[m] = mfma16(a, B0, a0[m]);
      a1[m] = mfma16(a, B1, a1[m]);
    }
  }
  float bb0 = bias[w * 32 + r], bb1 = bias[w * 32 + 16 + r];
#pragma unroll
  for (int m = 0; m < 2; ++m)
#pragma unroll
    for (int q = 0; q < 4; ++q) {
      int row = m * 16 + ch * 4 + q;
      dst[row * LDH + w * 32 + r]      = (_Float16)fmaxf(a0[m][q] + bb0, 0.f);
      dst[row * LDH + w * 32 + 16 + r] = (_Float16)fmaxf(a1[m][q] + bb1, 0.f);
    }
}

// ---------------------------------------------------------------------------
// Output layer, 16-row slab (slab index wh), all 64 cols; + bias + LayerNorm.
// Result left in acc: C[row = wh*16 + ch*4 + q][col = t*16 + r].
// ---------------------------------------------------------------------------
__device__ __forceinline__ void out16(const _Float16* __restrict__ src,
                                      const half8* __restrict__ wpo,
                                      const float* __restrict__ bo,
                                      const float* __restrict__ g,
                                      const float* __restrict__ bt,
                                      f32x4 acc[4], int wh, int lane) {
  const int r = lane & 15, ch = lane >> 4;
#pragma unroll
  for (int t = 0; t < 4; ++t) acc[t] = (f32x4){0.f, 0.f, 0.f, 0.f};
#pragma unroll
  for (int s = 0; s < 4; ++s) {
    half8 a = *(const half8*)(src + (wh * 16 + r) * LDH + s * 32 + ch * 8);
#pragma unroll
    for (int t = 0; t < 4; ++t)
      acc[t] = mfma16(a, wpo[(s * 4 + ch) * 64 + t * 16 + r], acc[t]);
  }
  float g4[4], b4[4];
#pragma unroll
  for (int t = 0; t < 4; ++t) {
    float bv = bo[t * 16 + r];
#pragma unroll
    for (int q = 0; q < 4; ++q) acc[t][q] += bv;
    g4[t] = g[t * 16 + r]; b4[t] = bt[t * 16 + r];
  }
#pragma unroll
  for (int q = 0; q < 4; ++q) {
    float s1 = 0.f, s2 = 0.f;
#pragma unroll
    for (int t = 0; t < 4; ++t) { float v = acc[t][q]; s1 += v; s2 += v * v; }
#pragma unroll
    for (int mk = 1; mk < 16; mk <<= 1) {
      s1 += __shfl_xor(s1, mk); s2 += __shfl_xor(s2, mk);
    }
    float mu = s1 * (1.f / 64);
    float rs = rsqrtf(s2 * (1.f / 64) - mu * mu + 1e-5f);
#pragma unroll
    for (int t = 0; t < 4; ++t)
      acc[t][q] = (acc[t][q] - mu) * rs * g4[t] + b4[t];
  }
}

// ---------------------------------------------------------------------------
struct EdgeP {
  const float* edge_attr; const int* edge_index; const int* batch;
  const _Float16* x_h; const _Float16* u_h; const _Float16* wp;
  const float *eBin, *eBh, *eBout, *eG, *eBt;
  const float *aBin, *aBh, *aBout, *aG, *aBt;
  float* agg;
};

// 32 edges/block, 256 threads. Waves 0-1: e-MLP; waves 2-3: a-MLP concurrent.
// 5 barrier stages: stage | L1 | h0 | h1 | out | combine.
// LDS = 14848 + 3*8704 = 40960 B -> exactly 4 blocks/CU (160 KiB).
__global__ __launch_bounds__(256, 4) void edge_kernel(EdgeP p) {
  __shared__ __align__(16) _Float16 sIn[32 * LD1];   // staging; e-pong after L1
  __shared__ __align__(16) _Float16 sE[32 * LDH];    // e ping
  __shared__ __align__(16) _Float16 sA2[32 * LDH];   // a ping
  __shared__ __align__(16) _Float16 sP[32 * LDH];    // a pong; f32 e-buf at end
  const int tid = threadIdx.x, lane = tid & 63, w = tid >> 6;
  const int r = lane & 15, ch = lane >> 4;
  const int e0 = blockIdx.x * 32;

  // S0: stage neigh = [x[src] | x[tgt] | edge_attr | u[batch[src]] | 0] f16
  for (int idx = tid; idx < 32 * 32; idx += 256) {
    int c = idx & 31, e = idx >> 5;
    if (c >= 28) continue;
    int col = c * 8;
    half8 v;
    if (col < 64) {
      int s = p.edge_index[e0 + e];
      v = *(const half8*)(p.x_h + (size_t)s * 64 + col);
    } else if (col < 128) {
      int t = p.edge_index[N_EDGES + e0 + e];
      v = *(const half8*)(p.x_h + (size_t)t * 64 + col - 64);
    } else if (col < 192) {
      const float* ea = p.edge_attr + (size_t)(e0 + e) * 64 + (col - 128);
      v = cvt8(*(const float4*)ea, *(const float4*)(ea + 4));
    } else if (col < 208) {
      int s = p.edge_index[e0 + e];
      int eb = p.batch[s];
      v = *(const half8*)(p.u_h + eb * 16 + col - 192);
    } else {
      v = zero8();
    }
    *(half8*)(sIn + e * LD1 + col) = v;
  }
  __syncthreads();

  const bool isE = (w < 2);
  const int wh = isE ? w : (w - 2);   // 0/1: col-half for GEMMs, row-slab for out
  const int col0 = wh * 64;
  _Float16* ping = isE ? sE : sA2;
  _Float16* pong = isE ? sIn : sP;    // sIn reinterpreted [32][LDH] after L1
  const half8* w1 = (const half8*)(p.wp + (isE ? O_EW1 : O_AW1));
  const half8* h0 = (const half8*)(p.wp + (isE ? O_EH0 : O_AH0));
  const half8* h1 = (const half8*)(p.wp + (isE ? O_EH1 : O_AH1));
  const half8* wo = (const half8*)(p.wp + (isE ? O_EWO : O_AWO));
  const float* bin = isE ? p.eBin : p.aBin;
  const float* bh  = isE ? p.eBh  : p.aBh;
  const float* bo  = isE ? p.eBout: p.aBout;
  const float* g   = isE ? p.eG   : p.aG;
  const float* bt  = isE ? p.eBt  : p.aBt;

  // S1..S3
  gemm64<7, LD1>(sIn,  ping, w1, bin,      col0, lane); __syncthreads();
  gemm64<4, LDH>(ping, pong, h0, bh,       col0, lane); __syncthreads();
  gemm64<4, LDH>(pong, ping, h1, bh + 128, col0, lane); __syncthreads();

  // S4: out + LN; e-waves park normalized e in sP (f32 32x64)
  f32x4 acc[4];
  out16(ping, wo, bo, g, bt, acc, wh, lane);
  float* eBuf = (float*)sP;
  if (isE) {
#pragma unroll
    for (int q = 0; q < 4; ++q) {
      int row = wh * 16 + ch * 4 + q;
#pragma unroll
      for (int t = 0; t < 4; ++t) eBuf[row * 64 + t * 16 + r] = acc[t][q];
    }
  }
  __syncthreads();

  // S5: a-waves combine + atomic scatter
  if (!isE) {
    int tq[4];
#pragma unroll
    for (int q = 0; q < 4; ++q)
      tq[q] = p.edge_index[N_EDGES + e0 + wh * 16 + ch * 4 + q];
#pragma unroll
    for (int q = 0; q < 4; ++q) {
      int row = wh * 16 + ch * 4 + q;
      float* ap = p.agg + (size_t)tq[q] * 64 + r;
#pragma unroll
      for (int t = 0; t < 4; ++t) {
        float sg = 1.f / (1.f + __expf(-acc[t][q]));
        atomicAdd(ap + t * 16, eBuf[row * 64 + t * 16 + r] * sg);
      }
    }
  }
}

// ---------------------------------------------------------------------------
struct NodeP {
  const float* agg; const _Float16* x_h; const _Float16* u_h;
  const _Float16* wp; const int* batch;
  const float *Bin, *Bh, *Bout, *G, *Bt;
  float* out;
};

// 32 nodes/block, 256 threads. LDS = 10752 + 2*8704 = 28160 B -> 5 blocks/CU.
__global__ __launch_bounds__(256, 5) void node_kernel(NodeP p) {
  __shared__ __align__(16) _Float16 sIn[32 * LDN];
  __shared__ __align__(16) _Float16 sA[32 * LDH];
  __shared__ __align__(16) _Float16 sB[32 * LDH];
  const int tid = threadIdx.x, lane = tid & 63, w = tid >> 6;
  const int r = lane & 15, ch = lane >> 4;
  const int n0 = blockIdx.x * 32;

  for (int idx = tid; idx < 32 * 32; idx += 256) {
    int c = idx & 31, e = idx >> 5;
    if (c >= 20) continue;
    int n = n0 + e, col = c * 8;
    half8 v;
    if (n >= N_NODES || col >= 144) {
      v = zero8();
    } else if (col < 64) {
      v = *(const half8*)(p.x_h + (size_t)n * 64 + col);
    } else if (col < 128) {
      const float* ag = p.agg + (size_t)n * 64 + (col - 64);
      v = cvt8(*(const float4*)ag, *(const float4*)(ag + 4));
    } else {
      v = *(const half8*)(p.u_h + p.batch[n] * 16 + col - 128);
    }
    *(half8*)(sIn + e * LDN + col) = v;
  }
  __syncthreads();

  gemm_m2<5, LDN>(sIn, sA, (const half8*)(p.wp + O_NW1), p.Bin, w, lane);
  __syncthreads();
  gemm_m2<4, LDH>(sA, sB, (const half8*)(p.wp + O_NH0), p.Bh, w, lane);
  __syncthreads();
  gemm_m2<4, LDH>(sB, sA, (const half8*)(p.wp + O_NH1), p.Bh + 128, w, lane);
  __syncthreads();
  if (w < 2) {
    f32x4 acc[4];
    out16(sA, (const half8*)(p.wp + O_NWO), p.Bout, p.G, p.Bt, acc, w, lane);
#pragma unroll
    for (int q = 0; q < 4; ++q) {
      int n = n0 + w * 16 + ch * 4 + q;
      if (n < N_NODES) {
#pragma unroll
        for (int t = 0; t < 4; ++t)
          p.out[(size_t)n * 64 + t * 16 + r] = acc[t][q];
      }
    }
  }
}

// ---------------------------------------------------------------------------
// Per-call pack: fp32 weights -> MFMA-B-fragment-packed fp16; x,u -> fp16.
// wdst[((s*4+c)*N + n)*8 + j] = W[s*32+c*8+j][n]  (0 if k >= Kreal)
// ---------------------------------------------------------------------------
#define GX 112
struct PackP {
  const float* src[12];
  int Kreal[12], Nlog[12], size[12], dstoff[12];
  const float* x; const float* u;
  _Float16* x_h; _Float16* u_h; _Float16* wdst;
};

__global__ void pack_kernel(PackP p) {
  int y = blockIdx.y;
  int idx = blockIdx.x * 256 + threadIdx.x;
  if (y < 12) {
    int sz = p.size[y];
    if (idx >= sz) return;
    int N = 1 << p.Nlog[y];
    int j = idx & 7, t = idx >> 3;
    int n = t & (N - 1);
    int sc = t >> p.Nlog[y];
    int c = sc & 3, s = sc >> 2;
    int k = s * 32 + c * 8 + j;
    p.wdst[p.dstoff[y] + idx] =
        (k < p.Kreal[y]) ? (_Float16)p.src[y][k * N + n] : (_Float16)0.f;
  } else {
    for (int i = idx; i < N_NODES * 64 / 8; i += GX * 256) {
      const float* s = p.x + (size_t)i * 8;
      *(half8*)(p.x_h + (size_t)i * 8) =
          cvt8(*(const float4*)s, *(const float4*)(s + 4));
    }
    for (int i = idx; i < 64 * 16 / 8; i += GX * 256) {
      const float* s = p.u + i * 8;
      *(half8*)(p.u_h + i * 8) =
          cvt8(*(const float4*)s, *(const float4*)(s + 4));
    }
  }
}

// ---------------------------------------------------------------------------
extern "C" void kernel_launch(void* const* d_in, const int* in_sizes, int n_in,
                              void* d_out, int out_size, void* d_ws, size_t ws_size,
                              hipStream_t stream) {
  const float* x = (const float*)d_in[0];
  const float* edge_attr = (const float*)d_in[1];
  const float* u = (const float*)d_in[2];
  const int* edge_index = (const int*)d_in[3];
  const int* batch = (const int*)d_in[4];

  char* ws = (char*)d_ws;
  float* agg = (float*)(ws + AGG_OFF);
  _Float16* x_h = (_Float16*)(ws + XH_OFF);
  _Float16* u_h = (_Float16*)(ws + UH_OFF);
  _Float16* wp = (_Float16*)(ws + WP_OFF);

  hipMemsetAsync(agg, 0, (size_t)N_NODES * 64 * sizeof(float), stream);

  PackP pk;
  const float* eWh = (const float*)d_in[7];
  const float* aWh = (const float*)d_in[15];
  const float* nWh = (const float*)d_in[23];
  const float* srcs[12] = {
      (const float*)d_in[5], eWh, eWh + 16384, (const float*)d_in[9],
      (const float*)d_in[13], aWh, aWh + 16384, (const float*)d_in[17],
      (const float*)d_in[21], nWh, nWh + 16384, (const float*)d_in[25]};
  const int kr[12] = {208, 128, 128, 128, 208, 128, 128, 128, 144, 128, 128, 128};
  const int nl[12] = {7, 7, 7, 6, 7, 7, 7, 6, 7, 7, 7, 6};
  const int sz[12] = {28672, 16384, 16384, 8192, 28672, 16384, 16384, 8192,
                      20480, 16384, 16384, 8192};
  const int off[12] = {O_EW1, O_EH0, O_EH1, O_EWO, O_AW1, O_AH0, O_AH1, O_AWO,
                       O_NW1, O_NH0, O_NH1, O_NWO};
  for (int i = 0; i < 12; ++i) {
    pk.src[i] = srcs[i]; pk.Kreal[i] = kr[i]; pk.Nlog[i] = nl[i];
    pk.size[i] = sz[i]; pk.dstoff[i] = off[i];
  }
  pk.x = x; pk.u = u; pk.x_h = x_h; pk.u_h = u_h; pk.wdst = wp;
  pack_kernel<<<dim3(GX, 13), 256, 0, stream>>>(pk);

  EdgeP ep;
  ep.edge_attr = edge_attr; ep.edge_index = edge_index; ep.batch = batch;
  ep.x_h = x_h; ep.u_h = u_h; ep.wp = wp;
  ep.eBin = (const float*)d_in[6];  ep.eBh = (const float*)d_in[8];
  ep.eBout = (const float*)d_in[10]; ep.eG = (const float*)d_in[11];
  ep.eBt = (const float*)d_in[12];
  ep.aBin = (const float*)d_in[14]; ep.aBh = (const float*)d_in[16];
  ep.aBout = (const float*)d_in[18]; ep.aG = (const float*)d_in[19];
  ep.aBt = (const float*)d_in[20];
  ep.agg = agg;
  edge_kernel<<<N_EDGES / 32, 256, 0, stream>>>(ep);

  NodeP np;
  np.agg = agg; np.x_h = x_h; np.u_h = u_h; np.wp = wp; np.batch = batch;
  np.Bin = (const float*)d_in[22]; np.Bh = (const float*)d_in[24];
  np.Bout = (const float*)d_in[26]; np.G = (const float*)d_in[27];
  np.Bt = (const float*)d_in[28];
  np.out = (float*)d_out;
  node_kernel<<<(N_NODES + 31) / 32, 256, 0, stream>>>(np);
}